// Round 8
// baseline (436.591 us; speedup 1.0000x reference)
//
#include <hip/hip_runtime.h>
#include <math.h>

#define TB  2
#define TT  2048
#define TC  768
#define TH  12
#define TDH 64
#define TI  3072
#define TM  (TB*TT)   // 4096 rows

typedef __attribute__((ext_vector_type(8))) __bf16 bf16x8;
typedef __attribute__((ext_vector_type(4))) __bf16 bf16x4;
typedef __attribute__((ext_vector_type(4))) float  f32x4;

__device__ __forceinline__ float gelu_tanh(float x) {
    float x3 = x * x * x;
    return 0.5f * x * (1.0f + tanhf(0.7978845608028654f * (x + 0.044715f * x3)));
}

// async global->LDS, 16B per lane (wave-uniform LDS base, lane l -> base+l*16)
__device__ __forceinline__ void gld_lds16(const void* g, void* l) {
    __builtin_amdgcn_global_load_lds(
        (const __attribute__((address_space(1))) unsigned int*)g,
        (__attribute__((address_space(3))) unsigned int*)l,
        16, 0, 0);
}

// ---------------------------------------------------------------------------
// bf16 MFMA GEMM, double-buffered LDS, XOR-swizzled chunks, 1 barrier/iter.
// (unchanged from R7)
// ---------------------------------------------------------------------------
#define BK 32

template<int BM_, int BN_, int WM_, int WN_>
__global__ __launch_bounds__(256)
void gemm_mfma(const __bf16* __restrict__ A, const __bf16* __restrict__ Bt,
               const float* __restrict__ b0, const float* __restrict__ b1,
               const float* __restrict__ b2, const float* __restrict__ resid,
               float* __restrict__ outf, __bf16* __restrict__ outb,
               int N, int K, int Kstride, size_t wt_stride, size_t out_stride,
               int ep)
{
    constexpr int WAVES_N = BN_ / WN_;
    constexpr int TMt = WM_ / 16, TNt = WN_ / 16;
    constexpr int AISS = BM_ / 64, BISS = BN_ / 64;
    constexpr int TILE = (BM_ + BN_) * BK;
    __shared__ __align__(16) __bf16 lds[2 * TILE];

    const int tid  = threadIdx.x;
    const int wave = tid >> 6, lane = tid & 63;
    const int wm = wave / WAVES_N, wn = wave % WAVES_N;
    const int m0 = blockIdx.y * BM_, n0 = blockIdx.x * BN_;
    const int z  = blockIdx.z;

    const __bf16* Bz = Bt + (size_t)z * wt_stride;
    const size_t Ksb = (size_t)Kstride * 2;              // row stride bytes
    const size_t kbaseB = (ep >= 3) ? (size_t)z * K * 2 : 0;
    const char* Ag = (const char*)A + (size_t)m0 * Ksb + kbaseB;
    const char* Bg = (const char*)Bz + (size_t)n0 * Ksb + kbaseB;
    const int srow = tid >> 2;
    const int scol = ((tid & 3) ^ ((tid >> 4) & 3)) * 16;
    const int wbase = wave * 1024;

    f32x4 acc[TMt][TNt];
    #pragma unroll
    for (int i = 0; i < TMt; ++i)
        #pragma unroll
        for (int j = 0; j < TNt; ++j)
            acc[i][j] = (f32x4){0.f, 0.f, 0.f, 0.f};

    const int arow = wm * WM_ + (lane & 15);
    const int brow = wn * WN_ + (lane & 15);
    const int koff = (((lane >> 4) ^ ((lane >> 2) & 3))) * 8;

    const int nIter = K / BK;

    auto stage = [&](int buf, int k0b) {
        char* base = (char*)lds + (size_t)buf * TILE * 2;
        #pragma unroll
        for (int s = 0; s < AISS; ++s)
            gld_lds16(Ag + (size_t)(srow + 64 * s) * Ksb + k0b + scol,
                      base + s * 4096 + wbase);
        char* bbase = base + BM_ * BK * 2;
        #pragma unroll
        for (int s = 0; s < BISS; ++s)
            gld_lds16(Bg + (size_t)(srow + 64 * s) * Ksb + k0b + scol,
                      bbase + s * 4096 + wbase);
    };

    stage(0, 0);
    int buf = 0;
    for (int it = 0; it < nIter; ++it) {
        __syncthreads();
        if (it + 1 < nIter) stage(buf ^ 1, (it + 1) * (BK * 2));

        const __bf16* As = lds + (size_t)buf * TILE;
        const __bf16* Bs = As + BM_ * BK;
        bf16x8 af[TMt], bfr[TNt];
        #pragma unroll
        for (int ti = 0; ti < TMt; ++ti)
            af[ti] = *(const bf16x8*)&As[(arow + ti * 16) * BK + koff];
        #pragma unroll
        for (int tj = 0; tj < TNt; ++tj)
            bfr[tj] = *(const bf16x8*)&Bs[(brow + tj * 16) * BK + koff];
        #pragma unroll
        for (int ti = 0; ti < TMt; ++ti)
            #pragma unroll
            for (int tj = 0; tj < TNt; ++tj)
                acc[ti][tj] = __builtin_amdgcn_mfma_f32_16x16x32_bf16(
                    af[ti], bfr[tj], acc[ti][tj], 0, 0, 0);
        buf ^= 1;
    }

    const int lrow = m0 + wm * WM_ + ((lane >> 4) << 2);
    const int lcol = n0 + wn * WN_ + (lane & 15);

    if (ep == 0) {
        const float* bias = (z == 0) ? b0 : (z == 1) ? b1 : b2;
        __bf16* outz = outb + (size_t)z * out_stride;
        if (z < 2) {
            #pragma unroll
            for (int tj = 0; tj < TNt; ++tj) {
                int n = lcol + tj * 16;
                float bj = bias[n];
                int h = n >> 6, d = n & 63;
                #pragma unroll
                for (int ti = 0; ti < TMt; ++ti)
                    #pragma unroll
                    for (int r = 0; r < 4; ++r) {
                        int m = lrow + ti * 16 + r;
                        int b = m >> 11, t = m & (TT - 1);
                        outz[((size_t)(b * TH + h) * TT + t) * TDH + d] =
                            (__bf16)(acc[ti][tj][r] + bj);
                    }
            }
        } else {
            #pragma unroll
            for (int tj = 0; tj < TNt; ++tj) {
                int n = lcol + tj * 16;
                float bj = bias[n];
                int h = n >> 6, d = n & 63;
                #pragma unroll
                for (int ti = 0; ti < TMt; ++ti) {
                    int m = lrow + ti * 16;
                    int b = m >> 11, t0 = m & (TT - 1);
                    bf16x4 pk;
                    #pragma unroll
                    for (int r = 0; r < 4; ++r)
                        pk[r] = (__bf16)(acc[ti][tj][r] + bj);
                    *(bf16x4*)(outz + ((size_t)(b * TH + h) * TDH + d) * TT + t0) = pk;
                }
            }
        }
    } else if (ep == 1) {
        #pragma unroll
        for (int tj = 0; tj < TNt; ++tj) {
            int n = lcol + tj * 16;
            float bj = b0[n];
            #pragma unroll
            for (int ti = 0; ti < TMt; ++ti)
                #pragma unroll
                for (int r = 0; r < 4; ++r) {
                    int m = lrow + ti * 16 + r;
                    outf[(size_t)m * N + n] =
                        acc[ti][tj][r] + bj + resid[(size_t)m * N + n];
                }
        }
    } else if (ep == 2) {
        #pragma unroll
        for (int tj = 0; tj < TNt; ++tj) {
            int n = lcol + tj * 16;
            float bj = b0[n];
            #pragma unroll
            for (int ti = 0; ti < TMt; ++ti)
                #pragma unroll
                for (int r = 0; r < 4; ++r) {
                    int m = lrow + ti * 16 + r;
                    outb[(size_t)m * N + n] = (__bf16)gelu_tanh(acc[ti][tj][r] + bj);
                }
        }
    } else if (ep == 3) {   // split-K fp32 partial
        float* outz = outf + (size_t)z * out_stride;
        #pragma unroll
        for (int tj = 0; tj < TNt; ++tj) {
            int n = lcol + tj * 16;
            #pragma unroll
            for (int ti = 0; ti < TMt; ++ti)
                #pragma unroll
                for (int r = 0; r < 4; ++r) {
                    int m = lrow + ti * 16 + r;
                    outz[(size_t)m * N + n] = acc[ti][tj][r];
                }
        }
    } else {                // ep == 4: split-K bf16 partial
        __bf16* outz = outb + (size_t)z * out_stride;
        #pragma unroll
        for (int tj = 0; tj < TNt; ++tj) {
            int n = lcol + tj * 16;
            #pragma unroll
            for (int ti = 0; ti < TMt; ++ti)
                #pragma unroll
                for (int r = 0; r < 4; ++r) {
                    int m = lrow + ti * 16 + r;
                    outz[(size_t)m * N + n] = (__bf16)acc[ti][tj][r];
                }
        }
    }
}

// ---------------------------------------------------------------------------
// Fused prep (unchanged)
// ---------------------------------------------------------------------------
__global__ __launch_bounds__(256)
void prep_kernel(const float* __restrict__ x,
                 const float* __restrict__ Wq, const float* __restrict__ Wk,
                 const float* __restrict__ Wv, const float* __restrict__ Wo,
                 const float* __restrict__ W1, const float* __restrict__ W2,
                 __bf16* __restrict__ x_bf, __bf16* __restrict__ WqkvT,
                 __bf16* __restrict__ WoT, __bf16* __restrict__ W1T,
                 __bf16* __restrict__ W2T)
{
    const size_t WSZ = (size_t)TC * TC;
    int bid = blockIdx.x;
    if (bid < 1536) {
        int i = (bid * 256 + threadIdx.x) * 8;
        float4 a = *(const float4*)(x + i);
        float4 b = *(const float4*)(x + i + 4);
        bf16x8 v;
        v[0] = (__bf16)a.x; v[1] = (__bf16)a.y; v[2] = (__bf16)a.z; v[3] = (__bf16)a.w;
        v[4] = (__bf16)b.x; v[5] = (__bf16)b.y; v[6] = (__bf16)b.z; v[7] = (__bf16)b.w;
        *(bf16x8*)(x_bf + i) = v;
        return;
    }
    bid -= 1536;
    const float* src; __bf16* dst; int K, N, tloc;
    if (bid < 2304) {
        int w = bid / 576; tloc = bid - w * 576;
        K = TC; N = TC;
        src = (w == 0) ? Wq : (w == 1) ? Wk : (w == 2) ? Wv : Wo;
        dst = (w < 3) ? (WqkvT + (size_t)w * WSZ) : WoT;
    } else if (bid < 4608) {
        tloc = bid - 2304; K = TC; N = TI; src = W1; dst = W1T;
    } else {
        tloc = bid - 4608; K = TI; N = TC; src = W2; dst = W2T;
    }
    int tiles_x = N >> 5;
    int n0 = (tloc % tiles_x) * 32, k0 = (tloc / tiles_x) * 32;

    __shared__ float tile[32][33];
    const int tx = threadIdx.x & 31, ty = threadIdx.x >> 5;
    #pragma unroll
    for (int i = 0; i < 32; i += 8)
        tile[ty + i][tx] = src[(size_t)(k0 + ty + i) * N + n0 + tx];
    __syncthreads();
    #pragma unroll
    for (int i = 0; i < 32; i += 8)
        dst[(size_t)(n0 + ty + i) * K + k0 + tx] = (__bf16)tile[tx][ty + i];
}

// ---------------------------------------------------------------------------
// LayerNorm (ddof=1, EPS=1e-4) core + variants (unchanged)
// ---------------------------------------------------------------------------
__device__ __forceinline__ void ln_core(float x0, float x1, float x2,
                                        const float* gs, const float* gb,
                                        float* out_row, __bf16* outbf_row, int tid)
{
    float s = x0 + x1 + x2;
    float q = x0 * x0 + x1 * x1 + x2 * x2;
    #pragma unroll
    for (int off = 32; off > 0; off >>= 1) {
        s += __shfl_down(s, off);
        q += __shfl_down(q, off);
    }
    __shared__ float partial[8];
    __shared__ float stats[2];
    int wid = tid >> 6, lane = tid & 63;
    if (lane == 0) { partial[wid] = s; partial[wid + 4] = q; }
    __syncthreads();
    if (tid == 0) {
        float S = partial[0] + partial[1] + partial[2] + partial[3];
        float Q = partial[4] + partial[5] + partial[6] + partial[7];
        float mean = S * (1.0f / (float)TC);
        float var = (Q - (float)TC * mean * mean) * (1.0f / (float)(TC - 1));
        stats[0] = mean;
        stats[1] = rsqrtf(var + 1e-4f);
    }
    __syncthreads();
    float mean = stats[0], rstd = stats[1];
    float y0 = gs[tid]       * ((x0 - mean) * rstd) + gb[tid];
    float y1 = gs[tid + 256] * ((x1 - mean) * rstd) + gb[tid + 256];
    float y2 = gs[tid + 512] * ((x2 - mean) * rstd) + gb[tid + 512];
    out_row[tid] = y0; out_row[tid + 256] = y1; out_row[tid + 512] = y2;
    if (outbf_row) {
        outbf_row[tid] = (__bf16)y0;
        outbf_row[tid + 256] = (__bf16)y1;
        outbf_row[tid + 512] = (__bf16)y2;
    }
}

__global__ __launch_bounds__(256)
void ln_fuse3(const float* __restrict__ p0, const float* __restrict__ p1,
              const float* __restrict__ p2, const float* __restrict__ bias,
              const float* __restrict__ resid,
              const float* __restrict__ gs, const float* __restrict__ gb,
              float* __restrict__ out, __bf16* __restrict__ out_bf)
{
    const int row = blockIdx.x, tid = threadIdx.x;
    const size_t o = (size_t)row * TC;
    float x0 = p0[o + tid]       + p1[o + tid]       + p2[o + tid]       + bias[tid]       + resid[o + tid];
    float x1 = p0[o + tid + 256] + p1[o + tid + 256] + p2[o + tid + 256] + bias[tid + 256] + resid[o + tid + 256];
    float x2 = p0[o + tid + 512] + p1[o + tid + 512] + p2[o + tid + 512] + bias[tid + 512] + resid[o + tid + 512];
    ln_core(x0, x1, x2, gs, gb, out + o, out_bf ? out_bf + o : nullptr, tid);
}

__global__ __launch_bounds__(256)
void ln_fuse2b(const __bf16* __restrict__ p0, const __bf16* __restrict__ p1,
               const float* __restrict__ bias, const float* __restrict__ resid,
               const float* __restrict__ gs, const float* __restrict__ gb,
               float* __restrict__ out)
{
    const int row = blockIdx.x, tid = threadIdx.x;
    const size_t o = (size_t)row * TC;
    float x0 = (float)p0[o + tid]       + (float)p1[o + tid]       + bias[tid]       + resid[o + tid];
    float x1 = (float)p0[o + tid + 256] + (float)p1[o + tid + 256] + bias[tid + 256] + resid[o + tid + 256];
    float x2 = (float)p0[o + tid + 512] + (float)p1[o + tid + 512] + bias[tid + 512] + resid[o + tid + 512];
    ln_core(x0, x1, x2, gs, gb, out + o, nullptr, tid);
}

// ---------------------------------------------------------------------------
// MFMA flash attention v4: BARRIER-FREE. Each wave loads its K and V
// fragments directly global->register in MFMA A-frag layout (per-instruction
// the wave covers 16 full cache lines, zero waste; L1 serves cross-wave
// re-reads). LDS holds only the per-wave P round-trip (no __syncthreads
// anywhere -> waves self-schedule, no barrier-coupled stalls).
// ---------------------------------------------------------------------------
#define AP 72

__global__ __launch_bounds__(256)
void attn_mfma(const __bf16* __restrict__ Q, const __bf16* __restrict__ K,
               const __bf16* __restrict__ Vt, __bf16* __restrict__ ctx)
{
    __shared__ __align__(16) __bf16 Ps[64 * AP];   // 9 KB, per-wave 16-row slices

    const int tid  = threadIdx.x;
    const int wave = tid >> 6, lane = tid & 63;
    const int c = lane & 15, g = lane >> 4;
    const int bh = blockIdx.y;
    const int qi = blockIdx.x;
    const int qt = (qi & 1) ? (31 - (qi >> 1)) : (qi >> 1);   // causal balance
    const int q_glob = qt * 64 + wave * 16 + c;

    const __bf16* Qb = Q  + (size_t)bh * TT * TDH;
    const __bf16* Kb = K  + (size_t)bh * TT * TDH;
    const __bf16* Vb = Vt + (size_t)bh * TDH * TT;

    // Q fragments (B-frag: lane c = q, halves at d = g*8 and 32+g*8)
    bf16x8 qf0 = *(const bf16x8*)(Qb + (size_t)q_glob * TDH + g * 8);
    bf16x8 qf1 = *(const bf16x8*)(Qb + (size_t)q_glob * TDH + 32 + g * 8);

    // V fragment row pointers (Vt row = d = 16*m2 + c)
    const __bf16* Vr0 = Vb + (size_t)(c)      * TT;
    const __bf16* Vr1 = Vb + (size_t)(16 + c) * TT;
    const __bf16* Vr2 = Vb + (size_t)(32 + c) * TT;
    const __bf16* Vr3 = Vb + (size_t)(48 + c) * TT;

    float m_i = -1e30f, l_i = 0.0f;
    f32x4 acc[4];
    #pragma unroll
    for (int m2 = 0; m2 < 4; ++m2) acc[m2] = (f32x4){0.f, 0.f, 0.f, 0.f};

    for (int kt = 0; kt <= qt; ++kt) {
        const __bf16* Kt = Kb + (size_t)kt * 64 * TDH;
        const int vcol = kt * 64 + g * 8;

        // K fragments: A-frag rows 16*g2 + c, d-halves g*8 / 32+g*8
        bf16x8 kf0[4], kf1[4];
        #pragma unroll
        for (int g2 = 0; g2 < 4; ++g2) {
            kf0[g2] = *(const bf16x8*)(Kt + (size_t)(16 * g2 + c) * TDH + g * 8);
            kf1[g2] = *(const bf16x8*)(Kt + (size_t)(16 * g2 + c) * TDH + 32 + g * 8);
        }
        // V fragments issued early; consumed after softmax (latency hidden)
        bf16x8 vf0[4], vf1[4];
        vf0[0] = *(const bf16x8*)(Vr0 + vcol);
        vf1[0] = *(const bf16x8*)(Vr0 + vcol + 32);
        vf0[1] = *(const bf16x8*)(Vr1 + vcol);
        vf1[1] = *(const bf16x8*)(Vr1 + vcol + 32);
        vf0[2] = *(const bf16x8*)(Vr2 + vcol);
        vf1[2] = *(const bf16x8*)(Vr2 + vcol + 32);
        vf0[3] = *(const bf16x8*)(Vr3 + vcol);
        vf1[3] = *(const bf16x8*)(Vr3 + vcol + 32);

        // S^T = K.Q^T
        f32x4 st[4];
        #pragma unroll
        for (int g2 = 0; g2 < 4; ++g2) {
            f32x4 z = (f32x4){0.f, 0.f, 0.f, 0.f};
            z = __builtin_amdgcn_mfma_f32_16x16x32_bf16(kf0[g2], qf0, z, 0, 0, 0);
            z = __builtin_amdgcn_mfma_f32_16x16x32_bf16(kf1[g2], qf1, z, 0, 0, 0);
            st[g2] = z;
        }

        // online softmax (per-lane q = q_glob; reduce over 4 lanes sharing c)
        float mx = -1e30f;
        if (kt == qt) {
            #pragma unroll
            for (int g2 = 0; g2 < 4; ++g2)
                #pragma unroll
                for (int r = 0; r < 4; ++r) {
                    int kcol = kt * 64 + 16 * g2 + 4 * g + r;
                    float v = (kcol > q_glob) ? -1e30f : st[g2][r] * 0.125f;
                    st[g2][r] = v;
                    mx = fmaxf(mx, v);
                }
        } else {
            #pragma unroll
            for (int g2 = 0; g2 < 4; ++g2)
                #pragma unroll
                for (int r = 0; r < 4; ++r) {
                    float v = st[g2][r] * 0.125f;
                    st[g2][r] = v;
                    mx = fmaxf(mx, v);
                }
        }
        mx = fmaxf(mx, __shfl_xor(mx, 16));
        mx = fmaxf(mx, __shfl_xor(mx, 32));
        float nm = fmaxf(m_i, mx);
        float corr = __expf(m_i - nm);
        float ps = 0.f;
        #pragma unroll
        for (int g2 = 0; g2 < 4; ++g2) {
            bf16x4 pk;
            #pragma unroll
            for (int r = 0; r < 4; ++r) {
                float p = __expf(st[g2][r] - nm);
                ps += p;
                pk[r] = (__bf16)p;
            }
            *(bf16x4*)&Ps[(wave * 16 + c) * AP + 16 * g2 + 4 * g] = pk;
        }
        ps += __shfl_xor(ps, 16);
        ps += __shfl_xor(ps, 32);
        l_i = l_i * corr + ps;
        m_i = nm;
        #pragma unroll
        for (int m2 = 0; m2 < 4; ++m2) {
            acc[m2][0] *= corr; acc[m2][1] *= corr;
            acc[m2][2] *= corr; acc[m2][3] *= corr;
        }

        // P round-trip (per-wave rows; same-wave write->read, lgkmcnt only)
        bf16x8 pf0 = *(const bf16x8*)&Ps[(wave * 16 + c) * AP + g * 8];
        bf16x8 pf1 = *(const bf16x8*)&Ps[(wave * 16 + c) * AP + 32 + g * 8];

        // O^T += V^T.P^T
        #pragma unroll
        for (int m2 = 0; m2 < 4; ++m2) {
            acc[m2] = __builtin_amdgcn_mfma_f32_16x16x32_bf16(vf0[m2], pf0, acc[m2], 0, 0, 0);
            acc[m2] = __builtin_amdgcn_mfma_f32_16x16x32_bf16(vf1[m2], pf1, acc[m2], 0, 0, 0);
        }
    }

    // epilogue: O^T[d][q] -> ctx[b][t=q][h*64+d], d = 16*m2 + 4*g + r
    const int b = bh / TH, h = bh - b * TH;
    float inv = 1.0f / l_i;
    #pragma unroll
    for (int m2 = 0; m2 < 4; ++m2) {
        bf16x4 o;
        #pragma unroll
        for (int r = 0; r < 4; ++r)
            o[r] = (__bf16)(acc[m2][r] * inv);
        *(bf16x4*)(ctx + ((size_t)b * TT + q_glob) * TC + h * TDH + 16 * m2 + 4 * g) = o;
    }
}

// ---------------------------------------------------------------------------
extern "C" void kernel_launch(void* const* d_in, const int* in_sizes, int n_in,
                              void* d_out, int out_size, void* d_ws, size_t ws_size,
                              hipStream_t stream)
{
    const float* x    = (const float*)d_in[0];
    const float* Wq   = (const float*)d_in[1];
    const float* bq   = (const float*)d_in[2];
    const float* Wk   = (const float*)d_in[3];
    const float* bk   = (const float*)d_in[4];
    const float* Wv   = (const float*)d_in[5];
    const float* bv   = (const float*)d_in[6];
    const float* Wo   = (const float*)d_in[7];
    const float* bo   = (const float*)d_in[8];
    const float* ln1s = (const float*)d_in[9];
    const float* ln1b = (const float*)d_in[10];
    const float* W1   = (const float*)d_in[11];
    const float* b1   = (const float*)d_in[12];
    const float* W2   = (const float*)d_in[13];
    const float* b2   = (const float*)d_in[14];
    const float* ln2s = (const float*)d_in[15];
    const float* ln2b = (const float*)d_in[16];
    float* out = (float*)d_out;

    const size_t MC  = (size_t)TM * TC;      // elems of a [TM,TC] buffer
    const size_t MCB = MC * 2;               // bytes of a bf16 [TM,TC]
    const size_t WSZ = (size_t)TC * TC;
    const size_t W12 = (size_t)TC * TI;

    char* W = (char*)d_ws;
    __bf16* qkvb  = (__bf16*)W;
    __bf16* x_bf  = (__bf16*)(W + 3 * MCB);
    float*  part0 = (float*)W;               // proj p0/p1 at [0,4MCB)
    float*  part2 = (float*)(W + 4 * MCB);   // proj p2 at [4,6)
    __bf16* u_bf  = (__bf16*)W;
    float*  h_f32 = (float*)(W + 4 * MCB);
    __bf16* ctxh  = (__bf16*)(W + 6 * MCB);  // ctx_bf / h_bf
    __bf16* p0b   = (__bf16*)(W + 6 * MCB);  // MLP2 partials (after MLP1)
    __bf16* wts   = (__bf16*)(W + 7 * MCB);
    __bf16* WqkvT = wts;
    __bf16* WoT   = WqkvT + 3 * WSZ;
    __bf16* W1T   = WoT + WSZ;
    __bf16* W2T   = W1T + W12;

    dim3 blk(256);

    prep_kernel<<<dim3(1536 + 6912), blk, 0, stream>>>(
        x, Wq, Wk, Wv, Wo, W1, W2, x_bf, WqkvT, WoT, W1T, W2T);

    // QKV (z: 0=Q, 1=K, 2=V^T), 64x128 tiles: grid 6x64x3 = 1152 blocks
    gemm_mfma<64, 128, 32, 64><<<dim3(TC / 128, TM / 64, 3), blk, 0, stream>>>(
        x_bf, WqkvT, bq, bk, bv, nullptr, nullptr, qkvb, TC, TC, TC, WSZ, MC, 0);

    attn_mfma<<<dim3(TT / 64, TB * TH), blk, 0, stream>>>(
        qkvb, qkvb + MC, qkvb + 2 * MC, ctxh);

    // out-proj split-K=3 (K=256 each): grid 6x64x3 = 1152, fp32 partials
    gemm_mfma<64, 128, 32, 64><<<dim3(TC / 128, TM / 64, 3), blk, 0, stream>>>(
        ctxh, WoT, nullptr, nullptr, nullptr, nullptr, part0, nullptr,
        TC, TC / 3, TC, 0, MC, 3);

    // LN1 fused: p0+p1+p2+bo+x -> LN -> h_f32 (in-place over p2) + h_bf(ctxh)
    ln_fuse3<<<dim3(TM), blk, 0, stream>>>(
        part0, part0 + MC, part2, bo, x, ln1s, ln1b, h_f32, ctxh);

    // MLP1 + gelu, 64x128: grid 24x64 = 1536 blocks -> u_bf
    gemm_mfma<64, 128, 32, 64><<<dim3(TI / 128, TM / 64, 1), blk, 0, stream>>>(
        ctxh, W1T, b1, nullptr, nullptr, nullptr, nullptr, u_bf, TI, TC, TC, 0, 0, 2);

    // MLP2 split-K=2 (K=1536 each): grid 6x64x2 = 768, bf16 partials
    gemm_mfma<64, 128, 32, 64><<<dim3(TC / 128, TM / 64, 2), blk, 0, stream>>>(
        u_bf, W2T, nullptr, nullptr, nullptr, nullptr, nullptr, p0b,
        TC, TI / 2, TI, 0, MC, 4);

    // LN2 fused: p0b+p1b+b2+h -> LN -> out
    ln_fuse2b<<<dim3(TM), blk, 0, stream>>>(
        p0b, p0b + MC, b2, h_f32, ln2s, ln2b, out);
}

// Round 9
// 323.211 us; speedup vs baseline: 1.3508x; 1.3508x over previous
//
#include <hip/hip_runtime.h>
#include <math.h>

#define TB  2
#define TT  2048
#define TC  768
#define TH  12
#define TDH 64
#define TI  3072
#define TM  (TB*TT)   // 4096 rows

typedef __attribute__((ext_vector_type(8))) __bf16 bf16x8;
typedef __attribute__((ext_vector_type(4))) __bf16 bf16x4;
typedef __attribute__((ext_vector_type(4))) float  f32x4;

__device__ __forceinline__ float gelu_tanh(float x) {
    float x3 = x * x * x;
    return 0.5f * x * (1.0f + tanhf(0.7978845608028654f * (x + 0.044715f * x3)));
}

// async global->LDS, 16B per lane (wave-uniform LDS base, lane l -> base+l*16)
__device__ __forceinline__ void gld_lds16(const void* g, void* l) {
    __builtin_amdgcn_global_load_lds(
        (const __attribute__((address_space(1))) unsigned int*)g,
        (__attribute__((address_space(3))) unsigned int*)l,
        16, 0, 0);
}

// ---------------------------------------------------------------------------
// bf16 MFMA GEMM, double-buffered LDS, XOR-swizzled chunks, 1 barrier/iter.
// ---------------------------------------------------------------------------
#define BK 32

template<int BM_, int BN_, int WM_, int WN_>
__global__ __launch_bounds__(256)
void gemm_mfma(const __bf16* __restrict__ A, const __bf16* __restrict__ Bt,
               const float* __restrict__ b0, const float* __restrict__ b1,
               const float* __restrict__ b2, const float* __restrict__ resid,
               float* __restrict__ outf, __bf16* __restrict__ outb,
               int N, int K, int Kstride, size_t wt_stride, size_t out_stride,
               int ep)
{
    constexpr int WAVES_N = BN_ / WN_;
    constexpr int TMt = WM_ / 16, TNt = WN_ / 16;
    constexpr int AISS = BM_ / 64, BISS = BN_ / 64;
    constexpr int TILE = (BM_ + BN_) * BK;
    __shared__ __align__(16) __bf16 lds[2 * TILE];

    const int tid  = threadIdx.x;
    const int wave = tid >> 6, lane = tid & 63;
    const int wm = wave / WAVES_N, wn = wave % WAVES_N;
    const int m0 = blockIdx.y * BM_, n0 = blockIdx.x * BN_;
    const int z  = blockIdx.z;

    const __bf16* Bz = Bt + (size_t)z * wt_stride;
    const size_t Ksb = (size_t)Kstride * 2;
    const size_t kbaseB = (ep >= 3) ? (size_t)z * K * 2 : 0;
    const char* Ag = (const char*)A + (size_t)m0 * Ksb + kbaseB;
    const char* Bg = (const char*)Bz + (size_t)n0 * Ksb + kbaseB;
    const int srow = tid >> 2;
    const int scol = ((tid & 3) ^ ((tid >> 4) & 3)) * 16;
    const int wbase = wave * 1024;

    f32x4 acc[TMt][TNt];
    #pragma unroll
    for (int i = 0; i < TMt; ++i)
        #pragma unroll
        for (int j = 0; j < TNt; ++j)
            acc[i][j] = (f32x4){0.f, 0.f, 0.f, 0.f};

    const int arow = wm * WM_ + (lane & 15);
    const int brow = wn * WN_ + (lane & 15);
    const int koff = (((lane >> 4) ^ ((lane >> 2) & 3))) * 8;

    const int nIter = K / BK;

    auto stage = [&](int buf, int k0b) {
        char* base = (char*)lds + (size_t)buf * TILE * 2;
        #pragma unroll
        for (int s = 0; s < AISS; ++s)
            gld_lds16(Ag + (size_t)(srow + 64 * s) * Ksb + k0b + scol,
                      base + s * 4096 + wbase);
        char* bbase = base + BM_ * BK * 2;
        #pragma unroll
        for (int s = 0; s < BISS; ++s)
            gld_lds16(Bg + (size_t)(srow + 64 * s) * Ksb + k0b + scol,
                      bbase + s * 4096 + wbase);
    };

    stage(0, 0);
    int buf = 0;
    for (int it = 0; it < nIter; ++it) {
        __syncthreads();
        if (it + 1 < nIter) stage(buf ^ 1, (it + 1) * (BK * 2));

        const __bf16* As = lds + (size_t)buf * TILE;
        const __bf16* Bs = As + BM_ * BK;
        bf16x8 af[TMt], bfr[TNt];
        #pragma unroll
        for (int ti = 0; ti < TMt; ++ti)
            af[ti] = *(const bf16x8*)&As[(arow + ti * 16) * BK + koff];
        #pragma unroll
        for (int tj = 0; tj < TNt; ++tj)
            bfr[tj] = *(const bf16x8*)&Bs[(brow + tj * 16) * BK + koff];
        #pragma unroll
        for (int ti = 0; ti < TMt; ++ti)
            #pragma unroll
            for (int tj = 0; tj < TNt; ++tj)
                acc[ti][tj] = __builtin_amdgcn_mfma_f32_16x16x32_bf16(
                    af[ti], bfr[tj], acc[ti][tj], 0, 0, 0);
        buf ^= 1;
    }

    const int lrow = m0 + wm * WM_ + ((lane >> 4) << 2);
    const int lcol = n0 + wn * WN_ + (lane & 15);

    if (ep == 0) {
        const float* bias = (z == 0) ? b0 : (z == 1) ? b1 : b2;
        __bf16* outz = outb + (size_t)z * out_stride;
        if (z < 2) {
            #pragma unroll
            for (int tj = 0; tj < TNt; ++tj) {
                int n = lcol + tj * 16;
                float bj = bias[n];
                int h = n >> 6, d = n & 63;
                #pragma unroll
                for (int ti = 0; ti < TMt; ++ti)
                    #pragma unroll
                    for (int r = 0; r < 4; ++r) {
                        int m = lrow + ti * 16 + r;
                        int b = m >> 11, t = m & (TT - 1);
                        outz[((size_t)(b * TH + h) * TT + t) * TDH + d] =
                            (__bf16)(acc[ti][tj][r] + bj);
                    }
            }
        } else {
            #pragma unroll
            for (int tj = 0; tj < TNt; ++tj) {
                int n = lcol + tj * 16;
                float bj = bias[n];
                int h = n >> 6, d = n & 63;
                #pragma unroll
                for (int ti = 0; ti < TMt; ++ti) {
                    int m = lrow + ti * 16;
                    int b = m >> 11, t0 = m & (TT - 1);
                    bf16x4 pk;
                    #pragma unroll
                    for (int r = 0; r < 4; ++r)
                        pk[r] = (__bf16)(acc[ti][tj][r] + bj);
                    *(bf16x4*)(outz + ((size_t)(b * TH + h) * TDH + d) * TT + t0) = pk;
                }
            }
        }
    } else if (ep == 1) {
        #pragma unroll
        for (int tj = 0; tj < TNt; ++tj) {
            int n = lcol + tj * 16;
            float bj = b0[n];
            #pragma unroll
            for (int ti = 0; ti < TMt; ++ti)
                #pragma unroll
                for (int r = 0; r < 4; ++r) {
                    int m = lrow + ti * 16 + r;
                    outf[(size_t)m * N + n] =
                        acc[ti][tj][r] + bj + resid[(size_t)m * N + n];
                }
        }
    } else if (ep == 2) {
        #pragma unroll
        for (int tj = 0; tj < TNt; ++tj) {
            int n = lcol + tj * 16;
            float bj = b0[n];
            #pragma unroll
            for (int ti = 0; ti < TMt; ++ti)
                #pragma unroll
                for (int r = 0; r < 4; ++r) {
                    int m = lrow + ti * 16 + r;
                    outb[(size_t)m * N + n] = (__bf16)gelu_tanh(acc[ti][tj][r] + bj);
                }
        }
    } else if (ep == 3) {   // split-K fp32 partial
        float* outz = outf + (size_t)z * out_stride;
        #pragma unroll
        for (int tj = 0; tj < TNt; ++tj) {
            int n = lcol + tj * 16;
            #pragma unroll
            for (int ti = 0; ti < TMt; ++ti)
                #pragma unroll
                for (int r = 0; r < 4; ++r) {
                    int m = lrow + ti * 16 + r;
                    outz[(size_t)m * N + n] = acc[ti][tj][r];
                }
        }
    } else {                // ep == 4: split-K bf16 partial
        __bf16* outz = outb + (size_t)z * out_stride;
        #pragma unroll
        for (int tj = 0; tj < TNt; ++tj) {
            int n = lcol + tj * 16;
            #pragma unroll
            for (int ti = 0; ti < TMt; ++ti)
                #pragma unroll
                for (int r = 0; r < 4; ++r) {
                    int m = lrow + ti * 16 + r;
                    outz[(size_t)m * N + n] = (__bf16)acc[ti][tj][r];
                }
        }
    }
}

// ---------------------------------------------------------------------------
// Fused prep (unchanged)
// ---------------------------------------------------------------------------
__global__ __launch_bounds__(256)
void prep_kernel(const float* __restrict__ x,
                 const float* __restrict__ Wq, const float* __restrict__ Wk,
                 const float* __restrict__ Wv, const float* __restrict__ Wo,
                 const float* __restrict__ W1, const float* __restrict__ W2,
                 __bf16* __restrict__ x_bf, __bf16* __restrict__ WqkvT,
                 __bf16* __restrict__ WoT, __bf16* __restrict__ W1T,
                 __bf16* __restrict__ W2T)
{
    const size_t WSZ = (size_t)TC * TC;
    int bid = blockIdx.x;
    if (bid < 1536) {
        int i = (bid * 256 + threadIdx.x) * 8;
        float4 a = *(const float4*)(x + i);
        float4 b = *(const float4*)(x + i + 4);
        bf16x8 v;
        v[0] = (__bf16)a.x; v[1] = (__bf16)a.y; v[2] = (__bf16)a.z; v[3] = (__bf16)a.w;
        v[4] = (__bf16)b.x; v[5] = (__bf16)b.y; v[6] = (__bf16)b.z; v[7] = (__bf16)b.w;
        *(bf16x8*)(x_bf + i) = v;
        return;
    }
    bid -= 1536;
    const float* src; __bf16* dst; int K, N, tloc;
    if (bid < 2304) {
        int w = bid / 576; tloc = bid - w * 576;
        K = TC; N = TC;
        src = (w == 0) ? Wq : (w == 1) ? Wk : (w == 2) ? Wv : Wo;
        dst = (w < 3) ? (WqkvT + (size_t)w * WSZ) : WoT;
    } else if (bid < 4608) {
        tloc = bid - 2304; K = TC; N = TI; src = W1; dst = W1T;
    } else {
        tloc = bid - 4608; K = TI; N = TC; src = W2; dst = W2T;
    }
    int tiles_x = N >> 5;
    int n0 = (tloc % tiles_x) * 32, k0 = (tloc / tiles_x) * 32;

    __shared__ float tile[32][33];
    const int tx = threadIdx.x & 31, ty = threadIdx.x >> 5;
    #pragma unroll
    for (int i = 0; i < 32; i += 8)
        tile[ty + i][tx] = src[(size_t)(k0 + ty + i) * N + n0 + tx];
    __syncthreads();
    #pragma unroll
    for (int i = 0; i < 32; i += 8)
        dst[(size_t)(n0 + ty + i) * K + k0 + tx] = (__bf16)tile[tx][ty + i];
}

// ---------------------------------------------------------------------------
// LayerNorm (ddof=1, EPS=1e-4) core + variants
// ---------------------------------------------------------------------------
__device__ __forceinline__ void ln_core(float x0, float x1, float x2,
                                        const float* gs, const float* gb,
                                        float* out_row, __bf16* outbf_row, int tid)
{
    float s = x0 + x1 + x2;
    float q = x0 * x0 + x1 * x1 + x2 * x2;
    #pragma unroll
    for (int off = 32; off > 0; off >>= 1) {
        s += __shfl_down(s, off);
        q += __shfl_down(q, off);
    }
    __shared__ float partial[8];
    __shared__ float stats[2];
    int wid = tid >> 6, lane = tid & 63;
    if (lane == 0) { partial[wid] = s; partial[wid + 4] = q; }
    __syncthreads();
    if (tid == 0) {
        float S = partial[0] + partial[1] + partial[2] + partial[3];
        float Q = partial[4] + partial[5] + partial[6] + partial[7];
        float mean = S * (1.0f / (float)TC);
        float var = (Q - (float)TC * mean * mean) * (1.0f / (float)(TC - 1));
        stats[0] = mean;
        stats[1] = rsqrtf(var + 1e-4f);
    }
    __syncthreads();
    float mean = stats[0], rstd = stats[1];
    float y0 = gs[tid]       * ((x0 - mean) * rstd) + gb[tid];
    float y1 = gs[tid + 256] * ((x1 - mean) * rstd) + gb[tid + 256];
    float y2 = gs[tid + 512] * ((x2 - mean) * rstd) + gb[tid + 512];
    out_row[tid] = y0; out_row[tid + 256] = y1; out_row[tid + 512] = y2;
    if (outbf_row) {
        outbf_row[tid] = (__bf16)y0;
        outbf_row[tid + 256] = (__bf16)y1;
        outbf_row[tid + 512] = (__bf16)y2;
    }
}

__global__ __launch_bounds__(256)
void ln_fuse3(const float* __restrict__ p0, const float* __restrict__ p1,
              const float* __restrict__ p2, const float* __restrict__ bias,
              const float* __restrict__ resid,
              const float* __restrict__ gs, const float* __restrict__ gb,
              float* __restrict__ out, __bf16* __restrict__ out_bf)
{
    const int row = blockIdx.x, tid = threadIdx.x;
    const size_t o = (size_t)row * TC;
    float x0 = p0[o + tid]       + p1[o + tid]       + p2[o + tid]       + bias[tid]       + resid[o + tid];
    float x1 = p0[o + tid + 256] + p1[o + tid + 256] + p2[o + tid + 256] + bias[tid + 256] + resid[o + tid + 256];
    float x2 = p0[o + tid + 512] + p1[o + tid + 512] + p2[o + tid + 512] + bias[tid + 512] + resid[o + tid + 512];
    ln_core(x0, x1, x2, gs, gb, out + o, out_bf ? out_bf + o : nullptr, tid);
}

__global__ __launch_bounds__(256)
void ln_fuse2b(const __bf16* __restrict__ p0, const __bf16* __restrict__ p1,
               const float* __restrict__ bias, const float* __restrict__ resid,
               const float* __restrict__ gs, const float* __restrict__ gb,
               float* __restrict__ out)
{
    const int row = blockIdx.x, tid = threadIdx.x;
    const size_t o = (size_t)row * TC;
    float x0 = (float)p0[o + tid]       + (float)p1[o + tid]       + bias[tid]       + resid[o + tid];
    float x1 = (float)p0[o + tid + 256] + (float)p1[o + tid + 256] + bias[tid + 256] + resid[o + tid + 256];
    float x2 = (float)p0[o + tid + 512] + (float)p1[o + tid + 512] + bias[tid + 512] + resid[o + tid + 512];
    ln_core(x0, x1, x2, gs, gb, out + o, nullptr, tid);
}

// ---------------------------------------------------------------------------
// MFMA flash attention (R6 version — best measured, 61.0 µs):
// KT=64, double-buffered K/V LDS, ONE barrier/iter, reg prefetch across
// barrier. LDS pitch 72, 46 KB.
// ---------------------------------------------------------------------------
#define AP 72

__global__ __launch_bounds__(256)
void attn_mfma(const __bf16* __restrict__ Q, const __bf16* __restrict__ K,
               const __bf16* __restrict__ Vt, __bf16* __restrict__ ctx)
{
    __shared__ __align__(16) __bf16 Ks[2][64 * AP];
    __shared__ __align__(16) __bf16 Vs[2][64 * AP];
    __shared__ __align__(16) __bf16 Ps[64 * AP];

    const int tid  = threadIdx.x;
    const int wave = tid >> 6, lane = tid & 63;
    const int c = lane & 15, g = lane >> 4;
    const int bh = blockIdx.y;
    const int qi = blockIdx.x;
    const int qt = (qi & 1) ? (31 - (qi >> 1)) : (qi >> 1);
    const int q_glob = qt * 64 + wave * 16 + c;

    const __bf16* Qb = Q  + (size_t)bh * TT * TDH;
    const __bf16* Kb = K  + (size_t)bh * TT * TDH;
    const __bf16* Vb = Vt + (size_t)bh * TDH * TT;

    bf16x8 qf0 = *(const bf16x8*)(Qb + (size_t)q_glob * TDH + g * 8);
    bf16x8 qf1 = *(const bf16x8*)(Qb + (size_t)q_glob * TDH + 32 + g * 8);

    const int sr = tid >> 3;
    const int sc = (tid & 7) * 8;

    bf16x8 k0 = *(const bf16x8*)(Kb + (size_t)sr * TDH + sc);
    bf16x8 k1 = *(const bf16x8*)(Kb + (size_t)(sr + 32) * TDH + sc);
    bf16x8 v0 = *(const bf16x8*)(Vb + (size_t)sr * TT + sc);
    bf16x8 v1 = *(const bf16x8*)(Vb + (size_t)(sr + 32) * TT + sc);

    float m_i = -1e30f, l_i = 0.0f;
    f32x4 acc[4];
    #pragma unroll
    for (int m2 = 0; m2 < 4; ++m2) acc[m2] = (f32x4){0.f, 0.f, 0.f, 0.f};

    for (int kt = 0; kt <= qt; ++kt) {
        const int b = kt & 1;
        *(bf16x8*)&Ks[b][sr * AP + sc]        = k0;
        *(bf16x8*)&Ks[b][(sr + 32) * AP + sc] = k1;
        *(bf16x8*)&Vs[b][sr * AP + sc]        = v0;
        *(bf16x8*)&Vs[b][(sr + 32) * AP + sc] = v1;
        if (kt < qt) {
            const int o = (kt + 1) * 64;
            k0 = *(const bf16x8*)(Kb + (size_t)(o + sr) * TDH + sc);
            k1 = *(const bf16x8*)(Kb + (size_t)(o + sr + 32) * TDH + sc);
            v0 = *(const bf16x8*)(Vb + (size_t)sr * TT + o + sc);
            v1 = *(const bf16x8*)(Vb + (size_t)(sr + 32) * TT + o + sc);
        }
        __syncthreads();

        f32x4 st[4];
        #pragma unroll
        for (int g2 = 0; g2 < 4; ++g2) {
            bf16x8 af0 = *(const bf16x8*)&Ks[b][(16 * g2 + c) * AP + g * 8];
            bf16x8 af1 = *(const bf16x8*)&Ks[b][(16 * g2 + c) * AP + 32 + g * 8];
            f32x4 z = (f32x4){0.f, 0.f, 0.f, 0.f};
            z = __builtin_amdgcn_mfma_f32_16x16x32_bf16(af0, qf0, z, 0, 0, 0);
            z = __builtin_amdgcn_mfma_f32_16x16x32_bf16(af1, qf1, z, 0, 0, 0);
            st[g2] = z;
        }

        float mx = -1e30f;
        if (kt == qt) {
            #pragma unroll
            for (int g2 = 0; g2 < 4; ++g2)
                #pragma unroll
                for (int r = 0; r < 4; ++r) {
                    int kcol = kt * 64 + 16 * g2 + 4 * g + r;
                    float v = (kcol > q_glob) ? -1e30f : st[g2][r] * 0.125f;
                    st[g2][r] = v;
                    mx = fmaxf(mx, v);
                }
        } else {
            #pragma unroll
            for (int g2 = 0; g2 < 4; ++g2)
                #pragma unroll
                for (int r = 0; r < 4; ++r) {
                    float v = st[g2][r] * 0.125f;
                    st[g2][r] = v;
                    mx = fmaxf(mx, v);
                }
        }
        mx = fmaxf(mx, __shfl_xor(mx, 16));
        mx = fmaxf(mx, __shfl_xor(mx, 32));
        float nm = fmaxf(m_i, mx);
        float corr = __expf(m_i - nm);
        float ps = 0.f;
        #pragma unroll
        for (int g2 = 0; g2 < 4; ++g2) {
            bf16x4 pk;
            #pragma unroll
            for (int r = 0; r < 4; ++r) {
                float p = __expf(st[g2][r] - nm);
                ps += p;
                pk[r] = (__bf16)p;
            }
            *(bf16x4*)&Ps[(wave * 16 + c) * AP + 16 * g2 + 4 * g] = pk;
        }
        ps += __shfl_xor(ps, 16);
        ps += __shfl_xor(ps, 32);
        l_i = l_i * corr + ps;
        m_i = nm;
        #pragma unroll
        for (int m2 = 0; m2 < 4; ++m2) {
            acc[m2][0] *= corr; acc[m2][1] *= corr;
            acc[m2][2] *= corr; acc[m2][3] *= corr;
        }

        bf16x8 pf0 = *(const bf16x8*)&Ps[(wave * 16 + c) * AP + g * 8];
        bf16x8 pf1 = *(const bf16x8*)&Ps[(wave * 16 + c) * AP + 32 + g * 8];
        #pragma unroll
        for (int m2 = 0; m2 < 4; ++m2) {
            bf16x8 vf0 = *(const bf16x8*)&Vs[b][(16 * m2 + c) * AP + g * 8];
            bf16x8 vf1 = *(const bf16x8*)&Vs[b][(16 * m2 + c) * AP + 32 + g * 8];
            acc[m2] = __builtin_amdgcn_mfma_f32_16x16x32_bf16(vf0, pf0, acc[m2], 0, 0, 0);
            acc[m2] = __builtin_amdgcn_mfma_f32_16x16x32_bf16(vf1, pf1, acc[m2], 0, 0, 0);
        }
    }

    const int b = bh / TH, h = bh - b * TH;
    float inv = 1.0f / l_i;
    #pragma unroll
    for (int m2 = 0; m2 < 4; ++m2) {
        bf16x4 o;
        #pragma unroll
        for (int r = 0; r < 4; ++r)
            o[r] = (__bf16)(acc[m2][r] * inv);
        *(bf16x4*)(ctx + ((size_t)b * TT + q_glob) * TC + h * TDH + 16 * m2 + 4 * g) = o;
    }
}

// ---------------------------------------------------------------------------
extern "C" void kernel_launch(void* const* d_in, const int* in_sizes, int n_in,
                              void* d_out, int out_size, void* d_ws, size_t ws_size,
                              hipStream_t stream)
{
    const float* x    = (const float*)d_in[0];
    const float* Wq   = (const float*)d_in[1];
    const float* bq   = (const float*)d_in[2];
    const float* Wk   = (const float*)d_in[3];
    const float* bk   = (const float*)d_in[4];
    const float* Wv   = (const float*)d_in[5];
    const float* bv   = (const float*)d_in[6];
    const float* Wo   = (const float*)d_in[7];
    const float* bo   = (const float*)d_in[8];
    const float* ln1s = (const float*)d_in[9];
    const float* ln1b = (const float*)d_in[10];
    const float* W1   = (const float*)d_in[11];
    const float* b1   = (const float*)d_in[12];
    const float* W2   = (const float*)d_in[13];
    const float* b2   = (const float*)d_in[14];
    const float* ln2s = (const float*)d_in[15];
    const float* ln2b = (const float*)d_in[16];
    float* out = (float*)d_out;

    const size_t MC  = (size_t)TM * TC;
    const size_t MCB = MC * 2;
    const size_t WSZ = (size_t)TC * TC;
    const size_t W12 = (size_t)TC * TI;

    char* W = (char*)d_ws;
    __bf16* qkvb  = (__bf16*)W;
    __bf16* x_bf  = (__bf16*)(W + 3 * MCB);
    float*  part0 = (float*)W;               // proj p0/p1 at [0,4MCB)
    float*  part2 = (float*)(W + 4 * MCB);   // proj p2 at [4,6)
    __bf16* u_bf  = (__bf16*)W;
    float*  h_f32 = (float*)(W + 4 * MCB);
    __bf16* ctxh  = (__bf16*)(W + 6 * MCB);  // ctx_bf / h_bf
    __bf16* p0b   = (__bf16*)(W + 6 * MCB);  // MLP2 partials (after MLP1)
    __bf16* wts   = (__bf16*)(W + 7 * MCB);
    __bf16* WqkvT = wts;
    __bf16* WoT   = WqkvT + 3 * WSZ;
    __bf16* W1T   = WoT + WSZ;
    __bf16* W2T   = W1T + W12;

    dim3 blk(256);

    prep_kernel<<<dim3(1536 + 6912), blk, 0, stream>>>(
        x, Wq, Wk, Wv, Wo, W1, W2, x_bf, WqkvT, WoT, W1T, W2T);

    // QKV (z: 0=Q, 1=K, 2=V^T), 128x128 tiles (R4 config): grid 6x32x3
    gemm_mfma<128, 128, 64, 64><<<dim3(TC / 128, TM / 128, 3), blk, 0, stream>>>(
        x_bf, WqkvT, bq, bk, bv, nullptr, nullptr, qkvb, TC, TC, TC, WSZ, MC, 0);

    attn_mfma<<<dim3(TT / 64, TB * TH), blk, 0, stream>>>(
        qkvb, qkvb + MC, qkvb + 2 * MC, ctxh);

    // out-proj split-K=3 (K=256 each): grid 6x64x3 = 1152, fp32 partials
    gemm_mfma<64, 128, 32, 64><<<dim3(TC / 128, TM / 64, 3), blk, 0, stream>>>(
        ctxh, WoT, nullptr, nullptr, nullptr, nullptr, part0, nullptr,
        TC, TC / 3, TC, 0, MC, 3);

    // LN1 fused: p0+p1+p2+bo+x -> LN -> h_f32 + h_bf(ctxh)
    ln_fuse3<<<dim3(TM), blk, 0, stream>>>(
        part0, part0 + MC, part2, bo, x, ln1s, ln1b, h_f32, ctxh);

    // MLP1 + gelu, 128x128 tiles (R4 config): grid 24x32 = 768 -> u_bf
    gemm_mfma<128, 128, 64, 64><<<dim3(TI / 128, TM / 128, 1), blk, 0, stream>>>(
        ctxh, W1T, b1, nullptr, nullptr, nullptr, nullptr, u_bf, TI, TC, TC, 0, 0, 2);

    // MLP2 split-K=2 (K=1536 each): grid 6x64x2 = 768, bf16 partials
    gemm_mfma<64, 128, 32, 64><<<dim3(TC / 128, TM / 64, 2), blk, 0, stream>>>(
        u_bf, W2T, nullptr, nullptr, nullptr, nullptr, nullptr, p0b,
        TC, TI / 2, TI, 0, MC, 4);

    // LN2 fused: p0b+p1b+b2+h -> LN -> out
    ln_fuse2b<<<dim3(TM), blk, 0, stream>>>(
        p0b, p0b + MC, b2, h_f32, ln2s, ln2b, out);
}